// Round 3
// baseline (359.942 us; speedup 1.0000x reference)
//
#include <hip/hip_runtime.h>
#include <hip/hip_cooperative_groups.h>
#include <math.h>

namespace cg = cooperative_groups;

#define EPSV 1e-5f

// Agent-scope (device-coherent, XCD-safe) helpers for cross-block exchange.
__device__ __forceinline__ void st_rel(float* p, float v) {
    __hip_atomic_store(p, v, __ATOMIC_RELEASE, __HIP_MEMORY_SCOPE_AGENT);
}
__device__ __forceinline__ float ld_acq(const float* p) {
    return __hip_atomic_load(p, __ATOMIC_ACQUIRE, __HIP_MEMORY_SCOPE_AGENT);
}

// One block per batch item. All activations live in LDS (~40 KB/block).
// Global traffic: x_in (768 KB), fc1w (401 KB, L3-broadcast), stat partials
// (~4 KB per BN boundary via agent-scope ops), out (4 B).
__global__ __launch_bounds__(256) void k_fused(
    const float* __restrict__ x_in,
    const float* __restrict__ w1,  const float* __restrict__ b1,
    const float* __restrict__ g1,  const float* __restrict__ be1,
    const float* __restrict__ w2,  const float* __restrict__ b2,
    const float* __restrict__ g2,  const float* __restrict__ be2,
    const float* __restrict__ w3,  const float* __restrict__ b3,
    const float* __restrict__ g3,  const float* __restrict__ be3,
    const float* __restrict__ fc1w, const float* __restrict__ fc1b,
    const float* __restrict__ fc2w, const float* __restrict__ fc2b,
    float* __restrict__ pp1, float* __restrict__ pp2,
    float* __restrict__ pp3, float* __restrict__ pf,
    float* __restrict__ out)
{
    __shared__ float sI[784];                       // wireframe 28x28
    __shared__ float a1[4 * 784];                   // conv1 out
    __shared__ float p1[4 * 196];                   // pool1
    __shared__ float a2[8 * 196];                   // conv2 out
    __shared__ float p2[8 * 49];                    // pool2
    __shared__ float a3[16 * 49];                   // conv3 out
    __shared__ __align__(16) float sx[784];         // bn3+relu flat
    __shared__ float sh[128];                       // fc1 out
    __shared__ float sw1[36], sw2[288], sw3[1152];
    __shared__ float scs[16], sfs[16];
    __shared__ double sred[32];

    const int tid  = threadIdx.x;
    const int lane = tid & 63;
    const int wv   = tid >> 6;          // wave id 0..3
    const int b    = blockIdx.x;
    cg::grid_group grid = cg::this_grid();

    // ---- P0: init ----
    for (int i = tid; i < 784;  i += 256) sI[i]  = 0.0f;
    for (int i = tid; i < 288;  i += 256) sw2[i] = w2[i];
    for (int i = tid; i < 1152; i += 256) sw3[i] = w3[i];
    if (tid < 36) sw1[tid] = w1[tid];
    __syncthreads();

    // ---- P1: wireframe scatter-max (each point hits a 2x2 patch; vals >= 0)
    for (int e = tid; e < 512; e += 256) {
        const float* xe = x_in + ((size_t)b * 512 + e) * 3;
        float p  = xe[0];
        float tx = xe[1] * 28.0f;
        float ty = xe[2] * 28.0f;
        int x0 = (int)floorf(tx); float fx = tx - (float)x0;
        int y0 = (int)floorf(ty); float fy = ty - (float)y0;
        float kx[2] = {1.0f - fx, fx};
        float ky[2] = {1.0f - fy, fy};
        #pragma unroll
        for (int dx = 0; dx < 2; ++dx) {
            int gx = x0 + dx;
            if (gx < 0 || gx > 27) continue;
            #pragma unroll
            for (int dy = 0; dy < 2; ++dy) {
                int gy = y0 + dy;
                if (gy < 0 || gy > 27) continue;
                float v = p * (kx[dx] * ky[dy]);
                atomicMax((int*)&sI[gx * 28 + gy], __float_as_int(v));
            }
        }
    }
    __syncthreads();

    // ---- P2: conv1 (wave wv -> channel wv), stats in registers ----
    {
        const float bias = b1[wv];
        float ls = 0.0f, lq = 0.0f;
        for (int p = lane; p < 784; p += 64) {
            int i = p / 28, j = p % 28;
            float s = bias;
            #pragma unroll
            for (int a = 0; a < 3; ++a) {
                int ii = i + a - 1;
                if (ii < 0 || ii > 27) continue;
                #pragma unroll
                for (int c = 0; c < 3; ++c) {
                    int jj = j + c - 1;
                    if (jj < 0 || jj > 27) continue;
                    s += sw1[wv * 9 + a * 3 + c] * sI[ii * 28 + jj];
                }
            }
            a1[wv * 784 + p] = s;
            ls += s; lq += s * s;
        }
        #pragma unroll
        for (int off = 32; off; off >>= 1) {
            ls += __shfl_down(ls, off);
            lq += __shfl_down(lq, off);
        }
        if (lane == 0) {
            st_rel(&pp1[b * 8 + wv],     ls);
            st_rel(&pp1[b * 8 + 4 + wv], lq);
        }
    }
    grid.sync();

    // ---- P3: bn1 stats reduce + bn1/relu/pool -> p1 ----
    if (tid < 64) {
        int c = tid >> 3, k = tid & 7;
        double t = 0.0;
        for (int i = k; i < 128; i += 8) t += (double)ld_acq(&pp1[i * 8 + c]);
        t += __shfl_down(t, 4); t += __shfl_down(t, 2); t += __shfl_down(t, 1);
        if (k == 0) sred[c] = t;
    }
    __syncthreads();
    if (tid < 4) {
        const double n = 128.0 * 784.0;
        double m = sred[tid] / n;
        double v = sred[4 + tid] / n - m * m;
        float scale = g1[tid] * rsqrtf((float)v + EPSV);
        scs[tid] = scale;
        sfs[tid] = be1[tid] - (float)m * scale;
    }
    __syncthreads();
    for (int idx = tid; idx < 784; idx += 256) {         // 4*196
        int c = idx / 196, pix = idx % 196;
        int r = pix / 14, col = pix % 14;
        const float* yb = a1 + c * 784;
        float scale = scs[c], shift = sfs[c];
        float v00 = yb[(2*r    )*28 + 2*col    ] * scale + shift;
        float v01 = yb[(2*r    )*28 + 2*col + 1] * scale + shift;
        float v10 = yb[(2*r + 1)*28 + 2*col    ] * scale + shift;
        float v11 = yb[(2*r + 1)*28 + 2*col + 1] * scale + shift;
        p1[idx] = fmaxf(fmaxf(fmaxf(v00, v01), fmaxf(v10, v11)), 0.0f);
    }
    __syncthreads();

    // ---- P4: conv2 (8 groups x 32 lanes) ----
    {
        const int o = tid >> 5, l32 = tid & 31;
        const float bias = b2[o];
        float ls = 0.0f, lq = 0.0f;
        for (int p = l32; p < 196; p += 32) {
            int i = p / 14, j = p % 14;
            float s = bias;
            #pragma unroll
            for (int c = 0; c < 4; ++c) {
                #pragma unroll
                for (int a = 0; a < 3; ++a) {
                    int ii = i + a - 1;
                    if (ii < 0 || ii > 13) continue;
                    #pragma unroll
                    for (int d = 0; d < 3; ++d) {
                        int jj = j + d - 1;
                        if (jj < 0 || jj > 13) continue;
                        s += sw2[((o * 4 + c) * 3 + a) * 3 + d] * p1[c * 196 + ii * 14 + jj];
                    }
                }
            }
            a2[o * 196 + p] = s;
            ls += s; lq += s * s;
        }
        #pragma unroll
        for (int off = 16; off; off >>= 1) {
            ls += __shfl_xor(ls, off);
            lq += __shfl_xor(lq, off);
        }
        if (l32 == 0) {
            st_rel(&pp2[b * 16 + o],     ls);
            st_rel(&pp2[b * 16 + 8 + o], lq);
        }
    }
    grid.sync();

    // ---- P5: bn2 stats + bn2/relu/pool -> p2 ----
    if (tid < 64) {
        int c = tid >> 2, k = tid & 3;
        double t = 0.0;
        for (int i = k; i < 128; i += 4) t += (double)ld_acq(&pp2[i * 16 + c]);
        t += __shfl_down(t, 2); t += __shfl_down(t, 1);
        if (k == 0) sred[c] = t;
    }
    __syncthreads();
    if (tid < 8) {
        const double n = 128.0 * 196.0;
        double m = sred[tid] / n;
        double v = sred[8 + tid] / n - m * m;
        float scale = g2[tid] * rsqrtf((float)v + EPSV);
        scs[tid] = scale;
        sfs[tid] = be2[tid] - (float)m * scale;
    }
    __syncthreads();
    for (int idx = tid; idx < 392; idx += 256) {         // 8*49
        int c = idx / 49, pix = idx % 49;
        int r = pix / 7, col = pix % 7;
        const float* yb = a2 + c * 196;
        float scale = scs[c], shift = sfs[c];
        float v00 = yb[(2*r    )*14 + 2*col    ] * scale + shift;
        float v01 = yb[(2*r    )*14 + 2*col + 1] * scale + shift;
        float v10 = yb[(2*r + 1)*14 + 2*col    ] * scale + shift;
        float v11 = yb[(2*r + 1)*14 + 2*col + 1] * scale + shift;
        p2[idx] = fmaxf(fmaxf(fmaxf(v00, v01), fmaxf(v10, v11)), 0.0f);
    }
    __syncthreads();

    // ---- P6: conv3 (16 groups x 16 lanes) ----
    {
        const int o = tid >> 4, l16 = tid & 15;
        const float bias = b3[o];
        float ls = 0.0f, lq = 0.0f;
        for (int p = l16; p < 49; p += 16) {
            int i = p / 7, j = p % 7;
            float s = bias;
            #pragma unroll
            for (int c = 0; c < 8; ++c) {
                #pragma unroll
                for (int a = 0; a < 3; ++a) {
                    int ii = i + a - 1;
                    if (ii < 0 || ii > 6) continue;
                    #pragma unroll
                    for (int d = 0; d < 3; ++d) {
                        int jj = j + d - 1;
                        if (jj < 0 || jj > 6) continue;
                        s += sw3[((o * 8 + c) * 3 + a) * 3 + d] * p2[c * 49 + ii * 7 + jj];
                    }
                }
            }
            a3[o * 49 + p] = s;
            ls += s; lq += s * s;
        }
        #pragma unroll
        for (int off = 8; off; off >>= 1) {
            ls += __shfl_xor(ls, off);
            lq += __shfl_xor(lq, off);
        }
        if (l16 == 0) {
            st_rel(&pp3[b * 32 + o],      ls);
            st_rel(&pp3[b * 32 + 16 + o], lq);
        }
    }
    grid.sync();

    // ---- P7: bn3 stats + bn3/relu -> sx ----
    if (tid < 128) {
        int c = tid >> 2, k = tid & 3;
        double t = 0.0;
        for (int i = k; i < 128; i += 4) t += (double)ld_acq(&pp3[i * 32 + c]);
        t += __shfl_down(t, 2); t += __shfl_down(t, 1);
        if (k == 0) sred[c] = t;
    }
    __syncthreads();
    if (tid < 16) {
        const double n = 128.0 * 49.0;
        double m = sred[tid] / n;
        double v = sred[16 + tid] / n - m * m;
        float scale = g3[tid] * rsqrtf((float)v + EPSV);
        scs[tid] = scale;
        sfs[tid] = be3[tid] - (float)m * scale;
    }
    __syncthreads();
    for (int idx = tid; idx < 784; idx += 256) {
        int c = idx / 49;
        sx[idx] = fmaxf(a3[idx] * scs[c] + sfs[c], 0.0f);
    }
    __syncthreads();

    // ---- P8: fc1 — wave wv handles rows [wv*32, wv*32+32), coalesced ----
    {
        const float4* xr = (const float4*)sx;            // 196 float4
        for (int r = 0; r < 32; ++r) {
            const int j = wv * 32 + r;
            const float4* wr = (const float4*)(fc1w + (size_t)j * 784);
            float s = 0.0f;
            #pragma unroll
            for (int k = 0; k < 3; ++k) {
                float4 w4 = wr[k * 64 + lane];
                float4 x4 = xr[k * 64 + lane];
                s += w4.x * x4.x + w4.y * x4.y + w4.z * x4.z + w4.w * x4.w;
            }
            if (lane < 4) {
                float4 w4 = wr[192 + lane];
                float4 x4 = xr[192 + lane];
                s += w4.x * x4.x + w4.y * x4.y + w4.z * x4.z + w4.w * x4.w;
            }
            #pragma unroll
            for (int off = 32; off; off >>= 1) s += __shfl_xor(s, off);
            if (lane == 0) sh[j] = fmaxf(s + fc1b[j], 0.0f);
        }
    }
    __syncthreads();

    // ---- P9: fc2 dot -> pf[b] ----
    if (tid < 64) {
        float v = sh[tid] * fc2w[tid] + sh[tid + 64] * fc2w[tid + 64];
        #pragma unroll
        for (int off = 32; off; off >>= 1) v += __shfl_xor(v, off);
        if (tid == 0) st_rel(&pf[b], v);
    }
    grid.sync();

    // ---- P10: batch mean (block 0 only) ----
    if (b == 0 && tid < 64) {
        float v = ld_acq(&pf[tid]) + ld_acq(&pf[tid + 64]);
        #pragma unroll
        for (int off = 32; off; off >>= 1) v += __shfl_xor(v, off);
        if (tid == 0) out[0] = v * (1.0f / 128.0f) + fc2b[0];
    }
}

// ---------------------------------------------------------------------------
extern "C" void kernel_launch(void* const* d_in, const int* in_sizes, int n_in,
                              void* d_out, int out_size, void* d_ws, size_t ws_size,
                              hipStream_t stream) {
    const float* x_in  = (const float*)d_in[0];
    const float* w1    = (const float*)d_in[1];
    const float* b1    = (const float*)d_in[2];
    const float* g1    = (const float*)d_in[3];
    const float* be1   = (const float*)d_in[4];
    const float* w2    = (const float*)d_in[5];
    const float* b2    = (const float*)d_in[6];
    const float* g2    = (const float*)d_in[7];
    const float* be2   = (const float*)d_in[8];
    const float* w3    = (const float*)d_in[9];
    const float* b3    = (const float*)d_in[10];
    const float* g3    = (const float*)d_in[11];
    const float* be3   = (const float*)d_in[12];
    const float* fc1w  = (const float*)d_in[13];
    const float* fc1b  = (const float*)d_in[14];
    const float* fc2w  = (const float*)d_in[15];
    const float* fc2b  = (const float*)d_in[16];

    float* ws  = (float*)d_ws;
    float* pp1 = ws;                    // 128*8
    float* pp2 = ws + 1024;             // 128*16
    float* pp3 = ws + 3072;             // 128*32
    float* pf  = ws + 7168;             // 128
    float* out = (float*)d_out;

    void* args[] = {
        (void*)&x_in,
        (void*)&w1, (void*)&b1, (void*)&g1, (void*)&be1,
        (void*)&w2, (void*)&b2, (void*)&g2, (void*)&be2,
        (void*)&w3, (void*)&b3, (void*)&g3, (void*)&be3,
        (void*)&fc1w, (void*)&fc1b, (void*)&fc2w, (void*)&fc2b,
        (void*)&pp1, (void*)&pp2, (void*)&pp3, (void*)&pf, (void*)&out
    };
    hipLaunchCooperativeKernel((void*)k_fused, dim3(128), dim3(256),
                               args, 0, stream);
}

// Round 4
// 132.440 us; speedup vs baseline: 2.7178x; 2.7178x over previous
//
#include <hip/hip_runtime.h>
#include <math.h>

#define EPSV 1e-5f

__device__ __forceinline__ float dot4(float4 a, float4 b) {
    return a.x * b.x + a.y * b.y + a.z * b.z + a.w * b.w;
}

// ws layout (floats):
//   pp1 @ 0    : 8  x 128  ([stat][block])  conv1 sum[4]+sumsq[4]
//   pp2 @ 1024 : 16 x 128
//   pp3 @ 3072 : 32 x 128
//   y1  @ 7168 : 128*4*784
//   y2  @ 408576 : 128*8*196
//   y3  @ 609280 : 128*16*49

// ---------------------------------------------------------------------------
// K1: wireframe scatter-max + conv1 (1->4) + per-block bn1 partials
// grid 128, block 256
// ---------------------------------------------------------------------------
__global__ __launch_bounds__(256) void k1_wire_conv1(
    const float* __restrict__ x_in, const float* __restrict__ w1,
    const float* __restrict__ b1,
    float* __restrict__ y1, float* __restrict__ pp1)
{
    __shared__ __align__(16) float sxin[1536];   // 512 x 3
    __shared__ float sI[784];
    __shared__ float sw[36];

    const int tid  = threadIdx.x;
    const int lane = tid & 63;
    const int wv   = tid >> 6;
    const int b    = blockIdx.x;

    // coalesced stage of x_in[b]
    {
        const float4* src = (const float4*)x_in + (size_t)b * 384;
        float4* dst = (float4*)sxin;
        for (int i = tid; i < 384; i += 256) dst[i] = src[i];
    }
    for (int i = tid; i < 784; i += 256) sI[i] = 0.0f;
    if (tid < 36) sw[tid] = w1[tid];
    __syncthreads();

    // scatter-max (products >= 0, so int-bit atomicMax is exact)
    for (int e = tid; e < 512; e += 256) {
        float p  = sxin[e * 3];
        float tx = sxin[e * 3 + 1] * 28.0f;
        float ty = sxin[e * 3 + 2] * 28.0f;
        int x0 = (int)floorf(tx); float fx = tx - (float)x0;
        int y0 = (int)floorf(ty); float fy = ty - (float)y0;
        float kx[2] = {1.0f - fx, fx};
        float ky[2] = {1.0f - fy, fy};
        #pragma unroll
        for (int dx = 0; dx < 2; ++dx) {
            int gx = x0 + dx;
            if (gx < 0 || gx > 27) continue;
            #pragma unroll
            for (int dy = 0; dy < 2; ++dy) {
                int gy = y0 + dy;
                if (gy < 0 || gy > 27) continue;
                float v = p * (kx[dx] * ky[dy]);
                atomicMax((int*)&sI[gx * 28 + gy], __float_as_int(v));
            }
        }
    }
    __syncthreads();

    // conv1: wave wv -> channel wv
    const float bias = b1[wv];
    float ls = 0.0f, lq = 0.0f;
    float* yb = y1 + ((size_t)b * 4 + wv) * 784;
    for (int p = lane; p < 784; p += 64) {
        int i = p / 28, j = p % 28;
        float s = bias;
        #pragma unroll
        for (int a = 0; a < 3; ++a) {
            int ii = i + a - 1;
            if (ii < 0 || ii > 27) continue;
            #pragma unroll
            for (int c = 0; c < 3; ++c) {
                int jj = j + c - 1;
                if (jj < 0 || jj > 27) continue;
                s += sw[wv * 9 + a * 3 + c] * sI[ii * 28 + jj];
            }
        }
        yb[p] = s;
        ls += s; lq += s * s;
    }
    #pragma unroll
    for (int off = 32; off; off >>= 1) {
        ls += __shfl_down(ls, off);
        lq += __shfl_down(lq, off);
    }
    if (lane == 0) {
        pp1[wv * 128 + b]       = ls;   // [stat][block]
        pp1[(4 + wv) * 128 + b] = lq;
    }
}

// ---------------------------------------------------------------------------
// K2: bn1 stat reduce + bn1/relu/pool + conv2 (4->8) + partials. grid 128.
// ---------------------------------------------------------------------------
__global__ __launch_bounds__(256) void k2_bnpool1_conv2(
    const float* __restrict__ y1, const float* __restrict__ pp1,
    const float* __restrict__ g1, const float* __restrict__ be1,
    const float* __restrict__ w2, const float* __restrict__ b2,
    float* __restrict__ y2, float* __restrict__ pp2)
{
    __shared__ __align__(16) float a1[3136];     // staged conv1 out 4x28x28
    __shared__ float p1s[784];                   // pooled 4x14x14
    __shared__ float sw2[288];
    __shared__ float scs[4], sfs[4];
    __shared__ double sred[8];

    const int tid = threadIdx.x;
    const int b   = blockIdx.x;

    // stage y1[b] (coalesced float4)
    {
        const float4* src = (const float4*)y1 + (size_t)b * 784;
        float4* dst = (float4*)a1;
        for (int i = tid; i < 784; i += 256) dst[i] = src[i];
    }
    for (int i = tid; i < 288; i += 256) sw2[i] = w2[i];

    // parallel coalesced stat reduce: 8 stats x 128, tps=32
    {
        const int c = tid >> 5, k = tid & 31;
        double t = 0.0;
        #pragma unroll
        for (int j = 0; j < 4; ++j) t += (double)pp1[c * 128 + k + j * 32];
        #pragma unroll
        for (int off = 16; off; off >>= 1) t += __shfl_xor(t, off);
        if (k == 0) sred[c] = t;
    }
    __syncthreads();
    if (tid < 4) {
        const double n = 128.0 * 784.0;
        double m = sred[tid] / n;
        double v = sred[4 + tid] / n - m * m;
        float scale = g1[tid] * rsqrtf((float)v + EPSV);
        scs[tid] = scale;
        sfs[tid] = be1[tid] - (float)m * scale;
    }
    __syncthreads();

    // bn + relu + pool from LDS
    for (int idx = tid; idx < 784; idx += 256) {
        int c = idx / 196, pix = idx % 196;
        int r = pix / 14, col = pix % 14;
        const float* yb = a1 + c * 784;
        float scale = scs[c], shift = sfs[c];
        float v00 = yb[(2*r    )*28 + 2*col    ] * scale + shift;
        float v01 = yb[(2*r    )*28 + 2*col + 1] * scale + shift;
        float v10 = yb[(2*r + 1)*28 + 2*col    ] * scale + shift;
        float v11 = yb[(2*r + 1)*28 + 2*col + 1] * scale + shift;
        p1s[idx] = fmaxf(fmaxf(fmaxf(v00, v01), fmaxf(v10, v11)), 0.0f);
    }
    __syncthreads();

    // conv2: 8 groups x 32 lanes
    const int o = tid >> 5, l32 = tid & 31;
    const float bias = b2[o];
    float ls = 0.0f, lq = 0.0f;
    float* yo = y2 + ((size_t)b * 8 + o) * 196;
    for (int p = l32; p < 196; p += 32) {
        int i = p / 14, j = p % 14;
        float s = bias;
        #pragma unroll
        for (int c = 0; c < 4; ++c) {
            #pragma unroll
            for (int a = 0; a < 3; ++a) {
                int ii = i + a - 1;
                if (ii < 0 || ii > 13) continue;
                #pragma unroll
                for (int d = 0; d < 3; ++d) {
                    int jj = j + d - 1;
                    if (jj < 0 || jj > 13) continue;
                    s += sw2[((o * 4 + c) * 3 + a) * 3 + d] * p1s[c * 196 + ii * 14 + jj];
                }
            }
        }
        yo[p] = s;
        ls += s; lq += s * s;
    }
    #pragma unroll
    for (int off = 16; off; off >>= 1) {
        ls += __shfl_xor(ls, off);
        lq += __shfl_xor(lq, off);
    }
    if (l32 == 0) {
        pp2[o * 128 + b]       = ls;
        pp2[(8 + o) * 128 + b] = lq;
    }
}

// ---------------------------------------------------------------------------
// K3: bn2 stat reduce + bn2/relu/pool + conv3 (8->16) + partials. grid 128.
// ---------------------------------------------------------------------------
__global__ __launch_bounds__(256) void k3_bnpool2_conv3(
    const float* __restrict__ y2, const float* __restrict__ pp2,
    const float* __restrict__ g2, const float* __restrict__ be2,
    const float* __restrict__ w3, const float* __restrict__ b3,
    float* __restrict__ y3, float* __restrict__ pp3)
{
    __shared__ __align__(16) float a2[1568];     // 8x14x14
    __shared__ float p2s[392];                   // 8x7x7
    __shared__ float sw3[1152];
    __shared__ float scs[8], sfs[8];
    __shared__ double sred[16];

    const int tid = threadIdx.x;
    const int b   = blockIdx.x;

    {
        const float4* src = (const float4*)y2 + (size_t)b * 392;
        float4* dst = (float4*)a2;
        for (int i = tid; i < 392; i += 256) dst[i] = src[i];
    }
    for (int i = tid; i < 1152; i += 256) sw3[i] = w3[i];

    // 16 stats x 128, tps=16
    {
        const int c = tid >> 4, k = tid & 15;
        double t = 0.0;
        #pragma unroll
        for (int j = 0; j < 8; ++j) t += (double)pp2[c * 128 + k + j * 16];
        #pragma unroll
        for (int off = 8; off; off >>= 1) t += __shfl_xor(t, off);
        if (k == 0) sred[c] = t;
    }
    __syncthreads();
    if (tid < 8) {
        const double n = 128.0 * 196.0;
        double m = sred[tid] / n;
        double v = sred[8 + tid] / n - m * m;
        float scale = g2[tid] * rsqrtf((float)v + EPSV);
        scs[tid] = scale;
        sfs[tid] = be2[tid] - (float)m * scale;
    }
    __syncthreads();

    for (int idx = tid; idx < 392; idx += 256) {
        int c = idx / 49, pix = idx % 49;
        int r = pix / 7, col = pix % 7;
        const float* yb = a2 + c * 196;
        float scale = scs[c], shift = sfs[c];
        float v00 = yb[(2*r    )*14 + 2*col    ] * scale + shift;
        float v01 = yb[(2*r    )*14 + 2*col + 1] * scale + shift;
        float v10 = yb[(2*r + 1)*14 + 2*col    ] * scale + shift;
        float v11 = yb[(2*r + 1)*14 + 2*col + 1] * scale + shift;
        p2s[idx] = fmaxf(fmaxf(fmaxf(v00, v01), fmaxf(v10, v11)), 0.0f);
    }
    __syncthreads();

    // conv3: 16 groups x 16 lanes
    const int o = tid >> 4, l16 = tid & 15;
    const float bias = b3[o];
    float ls = 0.0f, lq = 0.0f;
    float* yo = y3 + ((size_t)b * 16 + o) * 49;
    for (int p = l16; p < 49; p += 16) {
        int i = p / 7, j = p % 7;
        float s = bias;
        #pragma unroll
        for (int c = 0; c < 8; ++c) {
            #pragma unroll
            for (int a = 0; a < 3; ++a) {
                int ii = i + a - 1;
                if (ii < 0 || ii > 6) continue;
                #pragma unroll
                for (int d = 0; d < 3; ++d) {
                    int jj = j + d - 1;
                    if (jj < 0 || jj > 6) continue;
                    s += sw3[((o * 8 + c) * 3 + a) * 3 + d] * p2s[c * 49 + ii * 7 + jj];
                }
            }
        }
        yo[p] = s;
        ls += s; lq += s * s;
    }
    #pragma unroll
    for (int off = 8; off; off >>= 1) {
        ls += __shfl_xor(ls, off);
        lq += __shfl_xor(lq, off);
    }
    if (l16 == 0) {
        pp3[o * 128 + b]        = ls;
        pp3[(16 + o) * 128 + b] = lq;
    }
}

// ---------------------------------------------------------------------------
// K4: bn3 stat reduce + bn3/relu + fc1(half)+relu + fc2 partial + mean.
// grid 256: block = (b, half); half covers fc1 rows [half*64, half*64+64)
// ---------------------------------------------------------------------------
__global__ __launch_bounds__(256) void k4_bn3_fc(
    const float* __restrict__ y3, const float* __restrict__ pp3,
    const float* __restrict__ g3, const float* __restrict__ be3,
    const float* __restrict__ fc1w, const float* __restrict__ fc1b,
    const float* __restrict__ fc2w, const float* __restrict__ fc2b,
    float* __restrict__ out)
{
    __shared__ __align__(16) float ya[784];
    __shared__ __align__(16) float sx[1024];     // padded with zeros
    __shared__ float sh[64];
    __shared__ float scs[16], sfs[16];
    __shared__ double sred[32];

    const int tid  = threadIdx.x;
    const int lane = tid & 63;
    const int wv   = tid >> 6;
    const int b    = blockIdx.x >> 1;
    const int half = blockIdx.x & 1;

    {
        const float4* src = (const float4*)y3 + (size_t)b * 196;
        float4* dst = (float4*)ya;
        for (int i = tid; i < 196; i += 256) dst[i] = src[i];
    }

    // 32 stats x 128, tps=8
    {
        const int c = tid >> 3, k = tid & 7;
        double t = 0.0;
        #pragma unroll
        for (int j = 0; j < 16; ++j) t += (double)pp3[c * 128 + k + j * 8];
        #pragma unroll
        for (int off = 4; off; off >>= 1) t += __shfl_xor(t, off);
        if (k == 0) sred[c] = t;
    }
    __syncthreads();
    if (tid < 16) {
        const double n = 128.0 * 49.0;
        double m = sred[tid] / n;
        double v = sred[16 + tid] / n - m * m;
        float scale = g3[tid] * rsqrtf((float)v + EPSV);
        scs[tid] = scale;
        sfs[tid] = be3[tid] - (float)m * scale;
    }
    __syncthreads();

    for (int i = tid; i < 1024; i += 256)
        sx[i] = (i < 784) ? fmaxf(ya[i] * scs[i / 49] + sfs[i / 49], 0.0f) : 0.0f;
    __syncthreads();

    // fc1: wave wv handles rows j = half*64 + wv*16 + [0,16), 4 rows in flight
    {
        const float4* xr4 = (const float4*)sx;
        const float4 xa = xr4[lane];
        const float4 xb = xr4[64 + lane];
        const float4 xc = xr4[128 + lane];
        const float4 xd = xr4[192 + lane];       // zeros for lane >= 4
        const int jbase = half * 64 + wv * 16;
        for (int r0 = 0; r0 < 16; r0 += 4) {
            const float4* w0r = (const float4*)(fc1w + (size_t)(jbase + r0    ) * 784);
            const float4* w1r = (const float4*)(fc1w + (size_t)(jbase + r0 + 1) * 784);
            const float4* w2r = (const float4*)(fc1w + (size_t)(jbase + r0 + 2) * 784);
            const float4* w3r = (const float4*)(fc1w + (size_t)(jbase + r0 + 3) * 784);
            float s0 = dot4(w0r[lane], xa) + dot4(w0r[64+lane], xb) + dot4(w0r[128+lane], xc);
            float s1 = dot4(w1r[lane], xa) + dot4(w1r[64+lane], xb) + dot4(w1r[128+lane], xc);
            float s2 = dot4(w2r[lane], xa) + dot4(w2r[64+lane], xb) + dot4(w2r[128+lane], xc);
            float s3 = dot4(w3r[lane], xa) + dot4(w3r[64+lane], xb) + dot4(w3r[128+lane], xc);
            if (lane < 4) {                      // tail: floats [768, 784)
                s0 += dot4(w0r[192+lane], xd);
                s1 += dot4(w1r[192+lane], xd);
                s2 += dot4(w2r[192+lane], xd);
                s3 += dot4(w3r[192+lane], xd);
            }
            #pragma unroll
            for (int off = 32; off; off >>= 1) {
                s0 += __shfl_xor(s0, off);
                s1 += __shfl_xor(s1, off);
                s2 += __shfl_xor(s2, off);
                s3 += __shfl_xor(s3, off);
            }
            if (lane == 0) {
                const int lr = wv * 16 + r0;
                sh[lr    ] = fmaxf(s0 + fc1b[jbase + r0    ], 0.0f);
                sh[lr + 1] = fmaxf(s1 + fc1b[jbase + r0 + 1], 0.0f);
                sh[lr + 2] = fmaxf(s2 + fc1b[jbase + r0 + 2], 0.0f);
                sh[lr + 3] = fmaxf(s3 + fc1b[jbase + r0 + 3], 0.0f);
            }
        }
    }
    __syncthreads();

    // fc2 partial dot over this block's 64 h values -> atomic mean
    if (tid < 64) {
        float v = sh[tid] * fc2w[half * 64 + tid];
        #pragma unroll
        for (int off = 32; off; off >>= 1) v += __shfl_xor(v, off);
        if (tid == 0) atomicAdd(out, v * (1.0f / 128.0f));
    }
    if (blockIdx.x == 0 && tid == 0) atomicAdd(out, fc2b[0]);
}

// ---------------------------------------------------------------------------
extern "C" void kernel_launch(void* const* d_in, const int* in_sizes, int n_in,
                              void* d_out, int out_size, void* d_ws, size_t ws_size,
                              hipStream_t stream) {
    const float* x_in  = (const float*)d_in[0];
    const float* w1    = (const float*)d_in[1];
    const float* b1    = (const float*)d_in[2];
    const float* g1    = (const float*)d_in[3];
    const float* be1   = (const float*)d_in[4];
    const float* w2    = (const float*)d_in[5];
    const float* b2    = (const float*)d_in[6];
    const float* g2    = (const float*)d_in[7];
    const float* be2   = (const float*)d_in[8];
    const float* w3    = (const float*)d_in[9];
    const float* b3    = (const float*)d_in[10];
    const float* g3    = (const float*)d_in[11];
    const float* be3   = (const float*)d_in[12];
    const float* fc1w  = (const float*)d_in[13];
    const float* fc1b  = (const float*)d_in[14];
    const float* fc2w  = (const float*)d_in[15];
    const float* fc2b  = (const float*)d_in[16];

    float* ws  = (float*)d_ws;
    float* pp1 = ws;                    // 8 x 128
    float* pp2 = ws + 1024;             // 16 x 128
    float* pp3 = ws + 3072;             // 32 x 128
    float* y1  = ws + 7168;             // 128*4*784
    float* y2  = y1 + 401408;           // 128*8*196
    float* y3  = y2 + 200704;           // 128*16*49
    float* out = (float*)d_out;

    hipMemsetAsync(out, 0, sizeof(float), stream);

    k1_wire_conv1   <<<128, 256, 0, stream>>>(x_in, w1, b1, y1, pp1);
    k2_bnpool1_conv2<<<128, 256, 0, stream>>>(y1, pp1, g1, be1, w2, b2, y2, pp2);
    k3_bnpool2_conv3<<<128, 256, 0, stream>>>(y2, pp2, g2, be2, w3, b3, y3, pp3);
    k4_bn3_fc       <<<256, 256, 0, stream>>>(y3, pp3, g3, be3, fc1w, fc1b,
                                              fc2w, fc2b, out);
}